// Round 15
// baseline (73.049 us; speedup 1.0000x reference)
//
#include <hip/hip_runtime.h>
#include <hip/hip_bf16.h>
#include <stdint.h>

#define LOG2E 1.4426950408889634f
#define LN2   0.6931471805599453f

typedef float f32x4 __attribute__((ext_vector_type(4)));
typedef short s16x8 __attribute__((ext_vector_type(8)));
typedef short s16x4 __attribute__((ext_vector_type(4)));
typedef _Float16 f16x8 __attribute__((ext_vector_type(8)));
typedef _Float16 h2x2 __attribute__((ext_vector_type(2)));
typedef uint32_t u32x4 __attribute__((ext_vector_type(4)));
typedef uint32_t u32x2 __attribute__((ext_vector_type(2)));

__device__ inline float fexp2(float x) { return __builtin_amdgcn_exp2f(x); }
__device__ inline float frcp (float x) { return __builtin_amdgcn_rcpf(x); }
__device__ inline float flog2(float x) { return __builtin_amdgcn_logf(x); }
__device__ inline float ftanh(float x) {
  float e = fexp2(x * (2.0f * LOG2E));
  return 1.0f - 2.0f * frcp(e + 1.0f);
}
__device__ inline short f2h(float x) {
  union { _Float16 f; short s; } cv; cv.f = (_Float16)x; return cv.s;
}
__device__ inline float h2f(short s) {
  union { _Float16 f; short s; } cv; cv.s = s; return (float)cv.f;
}
__device__ inline uint32_t h2bits(h2x2 v) {
  uint32_t u; __builtin_memcpy(&u, &v, 4); return u;
}
__device__ inline h2x2 bits2h(uint32_t u) {
  h2x2 v; __builtin_memcpy(&v, &u, 4); return v;
}

// ---------------------------------------------------------------------------
// Kernel M: mega-prep — adjperm (blocks 0..255) + embcat fp16 hi/lo
//           (256..2303) + wprep fp16 hi/lo (2304..2335).
// ---------------------------------------------------------------------------
__global__ __launch_bounds__(256) void k_megaprep(
    const void* __restrict__ adj, uint32_t* __restrict__ adjt,
    const float* __restrict__ x, const int* __restrict__ verts,
    const float* __restrict__ emb, short* __restrict__ xh, short* __restrict__ xl,
    const float* __restrict__ w0, const float* __restrict__ w1,
    short* __restrict__ wf0h, short* __restrict__ wf0l,
    short* __restrict__ wf1h, short* __restrict__ wf1l)
{
  __shared__ uint32_t smode[4];
  int blk = blockIdx.x;
  int tid = threadIdx.x;

  if (blk < 256) {
    const uint32_t* w32 = (const uint32_t*)adj;
    uint32_t probe = w32[blk * 256 + tid];        // <256 KB: safe both modes
    uint32_t any = (probe > 1u) ? 1u : 0u;
    for (int m = 1; m < 64; m <<= 1) any |= __shfl_xor(any, m, 64);
    if ((tid & 63) == 0) smode[tid >> 6] = any;
    __syncthreads();
    uint32_t bytemode = smode[0] | smode[1] | smode[2] | smode[3];

    int t  = blk * 256 + tid;                     // (b, nt16, mc, c)
    int c  = t & 3;
    int mc = (t >> 2) & 31;
    int nt = (t >> 7) & 63;
    int b  = t >> 13;
    uint32_t* dst = adjt + (((size_t)(b * 64 + nt) * 32 + mc) * 128) + c * 32;

    if (bytemode) {
#pragma unroll 4
      for (int l15 = 0; l15 < 16; ++l15) {
        const uint8_t* src = (const uint8_t*)adj +
            ((size_t)(b * 1024 + nt * 16 + l15) * 1024 + mc * 32 + 4 * c);
        uint32_t lo = *(const uint32_t*)src;
        uint32_t hi = *(const uint32_t*)(src + 16);
        dst[2 * l15]     = lo * 0xFFu;
        dst[2 * l15 + 1] = hi * 0xFFu;
      }
    } else {
#pragma unroll 4
      for (int l15 = 0; l15 < 16; ++l15) {
        const uint32_t* src = (const uint32_t*)adj +
            ((size_t)(b * 1024 + nt * 16 + l15) * 1024 + mc * 32 + 4 * c);
        u32x4 qa = *(const u32x4*)src;
        u32x4 qb = *(const u32x4*)(src + 16);
        dst[2 * l15] = (qa[0] ? 0xFFu : 0u) | (qa[1] ? 0xFF00u : 0u) |
                       (qa[2] ? 0xFF0000u : 0u) | (qa[3] ? 0xFF000000u : 0u);
        dst[2 * l15 + 1] = (qb[0] ? 0xFFu : 0u) | (qb[1] ? 0xFF00u : 0u) |
                           (qb[2] ? 0xFF0000u : 0u) | (qb[3] ? 0xFF000000u : 0u);
      }
    }
  } else if (blk < 2304) {
    int i = (blk - 256) * 256 + tid;
    int row = i >> 6;
    int c2  = (i & 63) * 2;
    float v0, v1;
    if (c2 < 64) {
      v0 = x[row * 64 + c2];
      v1 = x[row * 64 + c2 + 1];
    } else {
      int v = verts[row];
      v0 = emb[(size_t)v * 64 + (c2 - 64)];
      v1 = emb[(size_t)v * 64 + (c2 - 64) + 1];
    }
    short h0 = f2h(v0), h1 = f2h(v1);
    short l0 = f2h(v0 - h2f(h0)), l1 = f2h(v1 - h2f(h1));
    ((uint32_t*)xh)[i] = (uint32_t)(uint16_t)h0 | ((uint32_t)(uint16_t)h1 << 16);
    ((uint32_t*)xl)[i] = (uint32_t)(uint16_t)l0 | ((uint32_t)(uint16_t)l1 << 16);
  } else {
    int t = (blk - 2304) * 256 + tid;   // 0..8191
    int layer = t >> 12;
    int r = t & 4095;
    int l = r & 63, slot = r >> 6;
    int l15 = l & 15, c = l >> 4;
    int FO  = layer ? 16 : 32;
    int FIN = layer ? 256 : 128;
    int ct  = layer ? (slot >> 3) : (slot >> 2);
    int kc  = layer ? (slot & 7)  : (slot & 3);
    int col = ct * 16 + l15;
    int h   = layer ? (col >> 4) : (col >> 5);
    int o   = col & (FO - 1);
    const float* wp = (layer ? w1 : w0) + (size_t)h * FIN * FO + o;
    short* dh = (layer ? wf1h : wf0h) + (size_t)r * 8;
    short* dl = (layer ? wf1l : wf0l) + (size_t)r * 8;
#pragma unroll
    for (int j = 0; j < 8; j++) {
      int k = kc * 32 + 4 * c + (j & 3) + ((j >> 2) << 4);
      float wv = wp[(size_t)k * FO];
      short hh = f2h(wv);
      dh[j] = hh;
      dl[j] = f2h(wv - h2f(hh));
    }
  }
}

// ---------------------------------------------------------------------------
// Kernel H: h_prime = xc @ w[h]  (split-FP16 Markidis, 3 MFMAs ~ fp32 exact),
// tanh -> s; writes lane-swizzled fp16 D/E tables (no atomics).
// hpb stored FP16, FRAGMENT-ARRANGED: [bh][mc(32)][ctl(CT)][lane(64)][8 f16]
// ---------------------------------------------------------------------------
template<int FIN, int FO>
__global__ __launch_bounds__(256) void k_hprime(
    const short* __restrict__ xcbh, const short* __restrict__ xcbl,
    const short* __restrict__ wfh, const short* __restrict__ wfl,
    const float* __restrict__ a_src, const float* __restrict__ a_dst,
    short* __restrict__ hpbh, float* __restrict__ sp,
    uint32_t* __restrict__ Dsw, uint32_t* __restrict__ Esw)
{
  constexpr int CT  = FO / 16;
  constexpr int CTB = 8 * FO / 16;
  constexpr int CTW = CTB / 4;
  constexpr int KC  = FIN / 32;

  int blk = blockIdx.x;              // 512
  int b   = blk >> 6;
  int ntg = blk & 63;
  int tid = threadIdx.x;
  int w4  = tid >> 6;
  int l   = tid & 63;
  int l15 = l & 15, c = l >> 4;

  int row = ntg * 16 + l15;
  const short* arowh = xcbh + ((size_t)(b * 1024 + row)) * FIN;
  const short* arowl = xcbl + ((size_t)(b * 1024 + row)) * FIN;

  f32x4 acc[CTW];
#pragma unroll
  for (int i = 0; i < CTW; i++) acc[i] = (f32x4){0.f, 0.f, 0.f, 0.f};

  for (int kc = 0; kc < KC; ++kc) {
    s16x4 ah0 = *(const s16x4*)(arowh + kc * 32 + 4 * c);
    s16x4 ah1 = *(const s16x4*)(arowh + kc * 32 + 4 * c + 16);
    s16x4 al0 = *(const s16x4*)(arowl + kc * 32 + 4 * c);
    s16x4 al1 = *(const s16x4*)(arowl + kc * 32 + 4 * c + 16);
    union { s16x8 s; f16x8 f; } afh, afl;
#pragma unroll
    for (int j = 0; j < 4; j++) {
      afh.s[j] = ah0[j]; afh.s[4 + j] = ah1[j];
      afl.s[j] = al0[j]; afl.s[4 + j] = al1[j];
    }
#pragma unroll
    for (int i = 0; i < CTW; i++) {
      int ct = w4 * CTW + i;
      union { s16x8 s; f16x8 f; } bfh, bfl;
      bfh.s = *(const s16x8*)(wfh + ((size_t)(ct * KC + kc) * 64 + l) * 8);
      bfl.s = *(const s16x8*)(wfl + ((size_t)(ct * KC + kc) * 64 + l) * 8);
      acc[i] = __builtin_amdgcn_mfma_f32_16x16x32_f16(afh.f, bfh.f, acc[i], 0, 0, 0);
      acc[i] = __builtin_amdgcn_mfma_f32_16x16x32_f16(afl.f, bfh.f, acc[i], 0, 0, 0);
      acc[i] = __builtin_amdgcn_mfma_f32_16x16x32_f16(afh.f, bfl.f, acc[i], 0, 0, 0);
    }
  }

  float s_acc[CTW][4];
  float d_acc[CTW][4];
#pragma unroll
  for (int i = 0; i < CTW; i++) {
    int ct  = w4 * CTW + i;
    int col = ct * 16 + l15;
    int h = col / FO, o = col % FO;
    float asv = a_src[h * FO + o];
    float adv = a_dst[h * FO + o];
    s16x4 hbh;
#pragma unroll
    for (int r = 0; r < 4; r++) {
      float hp = acc[i][r];
      hbh[r] = f2h(hp);
      float t = ftanh(hp);
      s_acc[i][r] = t * asv;
      d_acc[i][r] = t * adv;
    }
    int bh  = b * 8 + h;
    int ctl = o >> 4;
    size_t off = ((((size_t)(bh * 32 + (ntg >> 1))) * CT + ctl) * 64 + l) * 16 + (size_t)(ntg & 1) * 8;
    *(s16x4*)((char*)hpbh + off) = hbh;
  }

  constexpr int HW = (CTW * 16) / FO;   // heads per wave (=2)
#pragma unroll
  for (int hh = 0; hh < HW; ++hh) {
    float sred[4], dred[4];
#pragma unroll
    for (int r = 0; r < 4; r++) {
      float sv = 0.f, dv = 0.f;
#pragma unroll
      for (int i = hh * CT; i < (hh + 1) * CT; ++i) { sv += s_acc[i][r]; dv += d_acc[i][r]; }
      for (int m = 1; m < 16; m <<= 1) {
        sv += __shfl_xor(sv, m, 64);
        dv += __shfl_xor(dv, m, 64);
      }
      sred[r] = sv * LOG2E;
      dred[r] = dv * LOG2E;
    }
    if (l15 == 0) {
      int ct0 = w4 * CTW + hh * CT;
      int h   = (ct0 * 16) / FO;
      int bh  = b * 8 + h;
      f32x4 sv4; sv4[0] = sred[0]; sv4[1] = sred[1]; sv4[2] = sred[2]; sv4[3] = sred[3];
      *(f32x4*)&sp[bh * 1024 + ntg * 16 + 4 * c] = sv4;
      int s1 = (ntg >> 1) * 16 + 4 * c + 2 * (ntg & 1);
      h2x2 Da; Da[0] = (_Float16)fexp2(dred[0]); Da[1] = (_Float16)fexp2(dred[1]);
      h2x2 Db; Db[0] = (_Float16)fexp2(dred[2]); Db[1] = (_Float16)fexp2(dred[3]);
      h2x2 Ea; Ea[0] = (_Float16)fexp2(0.2f * dred[0]); Ea[1] = (_Float16)fexp2(0.2f * dred[1]);
      h2x2 Eb; Eb[0] = (_Float16)fexp2(0.2f * dred[2]); Eb[1] = (_Float16)fexp2(0.2f * dred[3]);
      u32x2 dw; dw[0] = h2bits(Da); dw[1] = h2bits(Db);
      u32x2 ew; ew[0] = h2bits(Ea); ew[1] = h2bits(Eb);
      *(u32x2*)&Dsw[bh * 512 + s1] = dw;
      *(u32x2*)&Esw[bh * 512 + s1] = ew;
    }
  }
}

// ---------------------------------------------------------------------------
// Kernel A: masked softmax(leaky(s+d)) @ h_prime — packed-fp16 score path.
//   NEW: hpb fragments are row-independent -> stage each mc-chunk pair into
//   LDS once per block (double-buffered, 1 barrier/iter); waves ds_read their
//   fragments from LDS. Cuts hpb L2/TD traffic 4x (TA/TD model of the 22us).
// ---------------------------------------------------------------------------
template<int CT, bool IS_L0>
__global__ __launch_bounds__(512, 8) void k_attn(
    const float* __restrict__ sp, const uint32_t* __restrict__ Dsw,
    const uint32_t* __restrict__ Esw,
    const short* __restrict__ hpbh,
    const uint32_t* __restrict__ adjt,
    const float* __restrict__ bias,
    void* __restrict__ outh, void* __restrict__ outl)
{
  constexpr int HALF_DW = CT * 256;          // dwords per mc-chunk
  constexpr int PER_THR = (2 * HALF_DW) / 512;   // 2 for CT=2, 1 for CT=1

  __shared__ uint32_t Dl[512];
  __shared__ uint32_t El[512];
  __shared__ float redm[8];
  __shared__ float racc[4][(CT + 1) * 4][64];
  __shared__ uint32_t hpst[2][2 * HALF_DW];  // [buf][half*HALF_DW + off]

  int i0   = blockIdx.x;          // 1024
  int xcd  = i0 & 7, slot = i0 >> 3;
  int bh   = xcd * 8 + (slot >> 4);
  int rb   = (slot & 15) * 64;
  int b    = bh >> 3;
  int tid  = threadIdx.x;
  int wid  = tid >> 6;            // 0..7
  int r16  = wid >> 1;            // row tile
  int half = wid & 1;             // mc half
  int l = tid & 63, l15 = l & 15, c = l >> 4;

  const uint32_t* hpdw = (const uint32_t*)hpbh + (size_t)bh * 32 * HALF_DW;

  uint32_t dw = Dsw[bh * 512 + tid];
  Dl[tid] = dw;
  El[tid] = Esw[bh * 512 + tid];
  h2x2 dv2 = bits2h(dw);
  float mv = fmaxf((float)dv2[0], (float)dv2[1]);
  for (int m = 1; m < 64; m <<= 1) mv = fmaxf(mv, __shfl_xor(mv, m, 64));
  if (l == 0) redm[wid] = mv;

  // stage t=0 chunk pair (mc=0 and mc=16) into buf 0
  {
    int flat = tid * PER_THR;
    int hf = flat / HALF_DW, off = flat - hf * HALF_DW;
    const uint32_t* src = hpdw + (size_t)(hf * 16) * HALF_DW + off;
    if (PER_THR == 2) { u32x2 v = *(const u32x2*)src; *(u32x2*)&hpst[0][flat] = v; }
    else hpst[0][flat] = *src;
  }
  __syncthreads();

  float Dmax = redm[0];
#pragma unroll
  for (int i = 1; i < 8; i++) Dmax = fmaxf(Dmax, redm[i]);
  float maxd = flog2(Dmax);

  int n = rb + r16 * 16 + l15;
  float svn = sp[bh * 1024 + n];
  float su  = svn + maxd;
  float ub  = fmaxf(su, 0.2f * su);      // >= true row max (leaky monotone)
  float cAf = fexp2(svn - ub + 8.0f);          // x256
  float cBf = fexp2(0.2f * svn - ub + 8.0f);   // x256
  h2x2 cA2; cA2[0] = (_Float16)cAf; cA2[1] = (_Float16)cAf;
  h2x2 cB2; cB2[0] = (_Float16)cBf; cB2[1] = (_Float16)cBf;
  const uint32_t* atile = adjt + ((size_t)(b * 64 + (rb >> 4) + r16) * 32) * 128 + l * 2;

  f32x4 acc[CT];
#pragma unroll
  for (int i = 0; i < CT; i++) acc[i] = (f32x4){0.f, 0.f, 0.f, 0.f};
  f32x4 accp = (f32x4){0.f, 0.f, 0.f, 0.f};
  union { s16x8 s; f16x8 f; } ones;
#pragma unroll
  for (int j = 0; j < 8; j++) ones.s[j] = (short)0x3C00;   // fp16 1.0

  const int mcBeg = half * 16;
  u32x2 nam = *(const u32x2*)(atile + (size_t)mcBeg * 128);

#pragma unroll
  for (int t = 0; t < 16; ++t) {
    int mc = mcBeg + t;
    u32x2 am = nam;
    // read this iter's fragments from LDS
    union { s16x8 s; f16x8 f; } cb[CT];
#pragma unroll
    for (int i = 0; i < CT; i++)
      cb[i].s = *(const s16x8*)&hpst[t & 1][half * HALF_DW + (i * 64 + l) * 4];
    u32x4 dq = *(const u32x4*)&Dl[mc * 16 + 4 * c];
    u32x4 eq = *(const u32x4*)&El[mc * 16 + 4 * c];

    if (t < 15) {
      nam = *(const u32x2*)(atile + (size_t)(mc + 1) * 128);
      // stage next chunk pair into the other buffer
      int flat = tid * PER_THR;
      int hf = flat / HALF_DW, off = flat - hf * HALF_DW;
      const uint32_t* src = hpdw + (size_t)(hf * 16 + t + 1) * HALF_DW + off;
      if (PER_THR == 2) { u32x2 v = *(const u32x2*)src; *(u32x2*)&hpst[(t + 1) & 1][flat] = v; }
      else hpst[(t + 1) & 1][flat] = *src;
    }

    union { u32x4 w; s16x8 s; f16x8 f; } pu;
#pragma unroll
    for (int tt = 0; tt < 4; ++tt) {
      h2x2 p2 = __builtin_elementwise_max(cA2 * bits2h(dq[tt]), cB2 * bits2h(eq[tt]));
      uint32_t msk = __builtin_amdgcn_perm(0u, am[tt >> 1],
                                           (tt & 1) ? 0x03030202u : 0x01010000u);
      pu.w[tt] = h2bits(p2) & msk;
    }

#pragma unroll
    for (int i = 0; i < CT; i++)
      acc[i] = __builtin_amdgcn_mfma_f32_16x16x32_f16(pu.f, cb[i].f, acc[i], 0, 0, 0);
    accp = __builtin_amdgcn_mfma_f32_16x16x32_f16(pu.f, ones.f, accp, 0, 0, 0);

    __syncthreads();   // next-buf writes complete; this-buf reads done
  }

  // pair-reduce the two mc-halves
  if (half == 1) {
#pragma unroll
    for (int i = 0; i < CT; i++)
#pragma unroll
      for (int r = 0; r < 4; r++) racc[r16][i * 4 + r][l] = acc[i][r];
#pragma unroll
    for (int r = 0; r < 4; r++) racc[r16][CT * 4 + r][l] = accp[r];
  }
  __syncthreads();
  if (half == 0) {
#pragma unroll
    for (int i = 0; i < CT; i++)
#pragma unroll
      for (int r = 0; r < 4; r++) acc[i][r] += racc[r16][i * 4 + r][l];
#pragma unroll
    for (int r = 0; r < 4; r++) {
      float rs  = accp[r] + racc[r16][CT * 4 + r][l];
      float inv = frcp(rs);
      int rown  = rb + r16 * 16 + 4 * c + r;
#pragma unroll
      for (int i = 0; i < CT; i++) {
        float v = acc[i][r] * inv;
        int col = i * 16 + l15;
        int h   = bh & 7;
        if (IS_L0) {
          v += bias[col];
          v = v > 0.f ? v : fexp2(v * LOG2E) - 1.f;   // elu
          size_t idx = ((size_t)(b * 1024 + rown)) * 256 + h * 32 + col;
          short vh = f2h(v);
          ((short*)outh)[idx] = vh;
          ((short*)outl)[idx] = f2h(v - h2f(vh));
        } else {
          ((float*)outh)[(((size_t)(b * 8 + h)) * 1024 + rown) * 16 + col] = v;
        }
      }
    }
  }
}

// ---------------------------------------------------------------------------
// Kernel F: mean over heads + bias + log_softmax(16)
// ---------------------------------------------------------------------------
__global__ __launch_bounds__(256) void k_final(
    const float* __restrict__ out1, const float* __restrict__ b1,
    float* __restrict__ out)
{
  int idx = blockIdx.x * 256 + threadIdx.x;
  if (idx >= 8192) return;
  int b = idx >> 10, n = idx & 1023;
  float v[16];
#pragma unroll
  for (int o = 0; o < 16; o++) v[o] = 0.f;
  for (int h = 0; h < 8; h++) {
    const float* p = out1 + (((size_t)(b * 8 + h)) * 1024 + n) * 16;
#pragma unroll
    for (int o = 0; o < 16; o++) v[o] += p[o];
  }
  float mx = -1e30f;
#pragma unroll
  for (int o = 0; o < 16; o++) {
    v[o] = v[o] * 0.125f + b1[o];
    mx = fmaxf(mx, v[o]);
  }
  float s = 0.f;
#pragma unroll
  for (int o = 0; o < 16; o++) s += fexp2((v[o] - mx) * LOG2E);
  float lse = flog2(s) * LN2;
#pragma unroll
  for (int o = 0; o < 16; o++) out[(size_t)idx * 16 + o] = v[o] - mx - lse;
}

// ---------------------------------------------------------------------------
extern "C" void kernel_launch(void* const* d_in, const int* in_sizes, int n_in,
                              void* d_out, int out_size, void* d_ws, size_t ws_size,
                              hipStream_t stream) {
  const float*   x     = (const float*)d_in[0];
  const int*     verts = (const int*)d_in[1];
  const void*    adj   = (const void*)d_in[2];   // int32 or uint8 — auto-detected
  const float*   emb   = (const float*)d_in[3];
  const float*   w0    = (const float*)d_in[4];
  const float*   as0   = (const float*)d_in[5];
  const float*   ad0   = (const float*)d_in[6];
  const float*   b0    = (const float*)d_in[7];
  const float*   w1    = (const float*)d_in[8];
  const float*   as1   = (const float*)d_in[9];
  const float*   ad1   = (const float*)d_in[10];
  const float*   b1    = (const float*)d_in[11];

  char* ws = (char*)d_ws;
  const size_t MB = 1ull << 20;
  const size_t KB = 1024;
  short* xcbh  = (short*)(ws);                         // 2 MB
  short* xcbl  = (short*)(ws + 2 * MB);                // 2 MB
  short* hpb0h = (short*)(ws + 4 * MB);                // 4 MB (dead after attn0)
  float* out1  = (float*)(ws + 4 * MB);                // 4 MB (aliases hpb0h)
  short* x1h   = (short*)(ws + 8 * MB);                // 4 MB
  short* x1l   = (short*)(ws + 12 * MB);               // 4 MB
  short* hpb1h = (short*)(ws + 16 * MB);               // 2 MB
  uint32_t* adjt = (uint32_t*)(ws + 18 * MB);          // 8 MB
  float* s0    = (float*)(ws + 26 * MB);               // 256 KB
  float* s1    = (float*)(ws + 26 * MB + 256 * KB);    // 256 KB
  short* wf0h  = (short*)(ws + 26 * MB + 512 * KB);    // 64 KB each
  short* wf0l  = (short*)(ws + 26 * MB + 576 * KB);
  short* wf1h  = (short*)(ws + 26 * MB + 640 * KB);
  short* wf1l  = (short*)(ws + 26 * MB + 704 * KB);
  uint32_t* Dsw0 = (uint32_t*)(ws + 26 * MB + 768 * KB);   // 128 KB each
  uint32_t* Esw0 = (uint32_t*)(ws + 26 * MB + 896 * KB);
  uint32_t* Dsw1 = (uint32_t*)(ws + 27 * MB);
  uint32_t* Esw1 = (uint32_t*)(ws + 27 * MB + 128 * KB);
  float* out   = (float*)d_out;

  k_megaprep<<<2336, 256, 0, stream>>>(adj, adjt, x, verts, emb, xcbh, xcbl,
                                       w0, w1, wf0h, wf0l, wf1h, wf1l);
  k_hprime<128, 32><<<512, 256, 0, stream>>>(xcbh, xcbl, wf0h, wf0l, as0, ad0,
                                             hpb0h, s0, Dsw0, Esw0);
  k_attn<2, true><<<1024, 512, 0, stream>>>(s0, Dsw0, Esw0, hpb0h, adjt,
                                            b0, (void*)x1h, (void*)x1l);
  k_hprime<256, 16><<<512, 256, 0, stream>>>(x1h, x1l, wf1h, wf1l, as1, ad1,
                                             hpb1h, s1, Dsw1, Esw1);
  k_attn<1, false><<<1024, 512, 0, stream>>>(s1, Dsw1, Esw1, hpb1h, adjt,
                                             b1, (void*)out1, nullptr);
  k_final<<<32, 256, 0, stream>>>(out1, b1, out);
}

// Round 16
// 66.839 us; speedup vs baseline: 1.0929x; 1.0929x over previous
//
#include <hip/hip_runtime.h>
#include <hip/hip_bf16.h>
#include <stdint.h>

#define LOG2E 1.4426950408889634f
#define LN2   0.6931471805599453f

typedef float f32x4 __attribute__((ext_vector_type(4)));
typedef short s16x8 __attribute__((ext_vector_type(8)));
typedef short s16x4 __attribute__((ext_vector_type(4)));
typedef _Float16 f16x8 __attribute__((ext_vector_type(8)));
typedef _Float16 h2x2 __attribute__((ext_vector_type(2)));
typedef uint32_t u32x4 __attribute__((ext_vector_type(4)));
typedef uint32_t u32x2 __attribute__((ext_vector_type(2)));

__device__ inline float fexp2(float x) { return __builtin_amdgcn_exp2f(x); }
__device__ inline float frcp (float x) { return __builtin_amdgcn_rcpf(x); }
__device__ inline float flog2(float x) { return __builtin_amdgcn_logf(x); }
__device__ inline float ftanh(float x) {
  float e = fexp2(x * (2.0f * LOG2E));
  return 1.0f - 2.0f * frcp(e + 1.0f);
}
__device__ inline short f2h(float x) {
  union { _Float16 f; short s; } cv; cv.f = (_Float16)x; return cv.s;
}
__device__ inline float h2f(short s) {
  union { _Float16 f; short s; } cv; cv.s = s; return (float)cv.f;
}
__device__ inline uint32_t h2bits(h2x2 v) {
  uint32_t u; __builtin_memcpy(&u, &v, 4); return u;
}
__device__ inline h2x2 bits2h(uint32_t u) {
  h2x2 v; __builtin_memcpy(&v, &u, 4); return v;
}

// ---------------------------------------------------------------------------
// Kernel M: prep — adjperm (blocks 0..255) + wprep fp16 hi/lo (256..287).
// (embcat now fused into k_hprime<...,true> — xcb round-trip eliminated.)
// ---------------------------------------------------------------------------
__global__ __launch_bounds__(256) void k_megaprep(
    const void* __restrict__ adj, uint32_t* __restrict__ adjt,
    const float* __restrict__ w0, const float* __restrict__ w1,
    short* __restrict__ wf0h, short* __restrict__ wf0l,
    short* __restrict__ wf1h, short* __restrict__ wf1l)
{
  __shared__ uint32_t smode[4];
  int blk = blockIdx.x;
  int tid = threadIdx.x;

  if (blk < 256) {
    const uint32_t* w32 = (const uint32_t*)adj;
    uint32_t probe = w32[blk * 256 + tid];        // <256 KB: safe both modes
    uint32_t any = (probe > 1u) ? 1u : 0u;
    for (int m = 1; m < 64; m <<= 1) any |= __shfl_xor(any, m, 64);
    if ((tid & 63) == 0) smode[tid >> 6] = any;
    __syncthreads();
    uint32_t bytemode = smode[0] | smode[1] | smode[2] | smode[3];

    int t  = blk * 256 + tid;                     // (b, nt16, mc, c)
    int c  = t & 3;
    int mc = (t >> 2) & 31;
    int nt = (t >> 7) & 63;
    int b  = t >> 13;
    uint32_t* dst = adjt + (((size_t)(b * 64 + nt) * 32 + mc) * 128) + c * 32;

    if (bytemode) {
#pragma unroll 4
      for (int l15 = 0; l15 < 16; ++l15) {
        const uint8_t* src = (const uint8_t*)adj +
            ((size_t)(b * 1024 + nt * 16 + l15) * 1024 + mc * 32 + 4 * c);
        uint32_t lo = *(const uint32_t*)src;
        uint32_t hi = *(const uint32_t*)(src + 16);
        dst[2 * l15]     = lo * 0xFFu;
        dst[2 * l15 + 1] = hi * 0xFFu;
      }
    } else {
#pragma unroll 4
      for (int l15 = 0; l15 < 16; ++l15) {
        const uint32_t* src = (const uint32_t*)adj +
            ((size_t)(b * 1024 + nt * 16 + l15) * 1024 + mc * 32 + 4 * c);
        u32x4 qa = *(const u32x4*)src;
        u32x4 qb = *(const u32x4*)(src + 16);
        dst[2 * l15] = (qa[0] ? 0xFFu : 0u) | (qa[1] ? 0xFF00u : 0u) |
                       (qa[2] ? 0xFF0000u : 0u) | (qa[3] ? 0xFF000000u : 0u);
        dst[2 * l15 + 1] = (qb[0] ? 0xFFu : 0u) | (qb[1] ? 0xFF00u : 0u) |
                           (qb[2] ? 0xFF0000u : 0u) | (qb[3] ? 0xFF000000u : 0u);
      }
    }
  } else {
    int t = (blk - 256) * 256 + tid;   // 0..8191
    int layer = t >> 12;
    int r = t & 4095;
    int l = r & 63, slot = r >> 6;
    int l15 = l & 15, c = l >> 4;
    int FO  = layer ? 16 : 32;
    int FIN = layer ? 256 : 128;
    int ct  = layer ? (slot >> 3) : (slot >> 2);
    int kc  = layer ? (slot & 7)  : (slot & 3);
    int col = ct * 16 + l15;
    int h   = layer ? (col >> 4) : (col >> 5);
    int o   = col & (FO - 1);
    const float* wp = (layer ? w1 : w0) + (size_t)h * FIN * FO + o;
    short* dh = (layer ? wf1h : wf0h) + (size_t)r * 8;
    short* dl = (layer ? wf1l : wf0l) + (size_t)r * 8;
#pragma unroll
    for (int j = 0; j < 8; j++) {
      int k = kc * 32 + 4 * c + (j & 3) + ((j >> 2) << 4);
      float wv = wp[(size_t)k * FO];
      short hh = f2h(wv);
      dh[j] = hh;
      dl[j] = f2h(wv - h2f(hh));
    }
  }
}

// ---------------------------------------------------------------------------
// Kernel H: h_prime = xc @ w[h]  (split-FP16 Markidis, 3 MFMAs ~ fp32 exact),
// tanh -> s; writes lane-swizzled fp16 D/E tables (no atomics).
// FUSE=true (layer 0): builds its 16-row x||emb tile in LDS (embcat fused).
// hpb stored FP16, FRAGMENT-ARRANGED: [bh][mc(32)][ctl(CT)][lane(64)][8 f16]
// ---------------------------------------------------------------------------
template<int FIN, int FO, bool FUSE>
__global__ __launch_bounds__(256) void k_hprime(
    const short* __restrict__ xcbh, const short* __restrict__ xcbl,
    const float* __restrict__ x, const int* __restrict__ verts,
    const float* __restrict__ emb,
    const short* __restrict__ wfh, const short* __restrict__ wfl,
    const float* __restrict__ a_src, const float* __restrict__ a_dst,
    short* __restrict__ hpbh, float* __restrict__ sp,
    uint32_t* __restrict__ Dsw, uint32_t* __restrict__ Esw)
{
  constexpr int CT  = FO / 16;
  constexpr int CTB = 8 * FO / 16;
  constexpr int CTW = CTB / 4;
  constexpr int KC  = FIN / 32;

  __shared__ short xsh[FUSE ? 16 : 1][FUSE ? 132 : 1];
  __shared__ short xsl[FUSE ? 16 : 1][FUSE ? 132 : 1];

  int blk = blockIdx.x;              // 512
  int b   = blk >> 6;
  int ntg = blk & 63;
  int tid = threadIdx.x;
  int w4  = tid >> 6;
  int l   = tid & 63;
  int l15 = l & 15, c = l >> 4;

  if constexpr (FUSE) {
    // ---- fused embcat: build 16x128 fp16 hi/lo tile for this block's rows ----
    int t8  = tid * 8;
    int row = t8 >> 7;          // 0..15
    int col = t8 & 127;         // multiple of 8
    int grow = b * 1024 + ntg * 16 + row;
    f32x4 va, vb;
    if (col < 64) {
      va = *(const f32x4*)&x[(size_t)grow * 64 + col];
      vb = *(const f32x4*)&x[(size_t)grow * 64 + col + 4];
    } else {
      int vv = verts[grow];
      va = *(const f32x4*)&emb[(size_t)vv * 64 + (col - 64)];
      vb = *(const f32x4*)&emb[(size_t)vv * 64 + (col - 64) + 4];
    }
#pragma unroll
    for (int j = 0; j < 8; j++) {
      float v = (j < 4) ? va[j] : vb[j - 4];
      short hh = f2h(v);
      xsh[row][col + j] = hh;
      xsl[row][col + j] = f2h(v - h2f(hh));
    }
    __syncthreads();
  }

  int row = ntg * 16 + l15;
  const short* arowh = FUSE ? nullptr : xcbh + ((size_t)(b * 1024 + row)) * FIN;
  const short* arowl = FUSE ? nullptr : xcbl + ((size_t)(b * 1024 + row)) * FIN;

  f32x4 acc[CTW];
#pragma unroll
  for (int i = 0; i < CTW; i++) acc[i] = (f32x4){0.f, 0.f, 0.f, 0.f};

  for (int kc = 0; kc < KC; ++kc) {
    s16x4 ah0, ah1, al0, al1;
    if constexpr (FUSE) {
      ah0 = *(const s16x4*)&xsh[l15][kc * 32 + 4 * c];
      ah1 = *(const s16x4*)&xsh[l15][kc * 32 + 4 * c + 16];
      al0 = *(const s16x4*)&xsl[l15][kc * 32 + 4 * c];
      al1 = *(const s16x4*)&xsl[l15][kc * 32 + 4 * c + 16];
    } else {
      ah0 = *(const s16x4*)(arowh + kc * 32 + 4 * c);
      ah1 = *(const s16x4*)(arowh + kc * 32 + 4 * c + 16);
      al0 = *(const s16x4*)(arowl + kc * 32 + 4 * c);
      al1 = *(const s16x4*)(arowl + kc * 32 + 4 * c + 16);
    }
    union { s16x8 s; f16x8 f; } afh, afl;
#pragma unroll
    for (int j = 0; j < 4; j++) {
      afh.s[j] = ah0[j]; afh.s[4 + j] = ah1[j];
      afl.s[j] = al0[j]; afl.s[4 + j] = al1[j];
    }
#pragma unroll
    for (int i = 0; i < CTW; i++) {
      int ct = w4 * CTW + i;
      union { s16x8 s; f16x8 f; } bfh, bfl;
      bfh.s = *(const s16x8*)(wfh + ((size_t)(ct * KC + kc) * 64 + l) * 8);
      bfl.s = *(const s16x8*)(wfl + ((size_t)(ct * KC + kc) * 64 + l) * 8);
      acc[i] = __builtin_amdgcn_mfma_f32_16x16x32_f16(afh.f, bfh.f, acc[i], 0, 0, 0);
      acc[i] = __builtin_amdgcn_mfma_f32_16x16x32_f16(afl.f, bfh.f, acc[i], 0, 0, 0);
      acc[i] = __builtin_amdgcn_mfma_f32_16x16x32_f16(afh.f, bfl.f, acc[i], 0, 0, 0);
    }
  }

  float s_acc[CTW][4];
  float d_acc[CTW][4];
#pragma unroll
  for (int i = 0; i < CTW; i++) {
    int ct  = w4 * CTW + i;
    int col = ct * 16 + l15;
    int h = col / FO, o = col % FO;
    float asv = a_src[h * FO + o];
    float adv = a_dst[h * FO + o];
    s16x4 hbh;
#pragma unroll
    for (int r = 0; r < 4; r++) {
      float hp = acc[i][r];
      hbh[r] = f2h(hp);
      float t = ftanh(hp);
      s_acc[i][r] = t * asv;
      d_acc[i][r] = t * adv;
    }
    int bh  = b * 8 + h;
    int ctl = o >> 4;
    size_t off = ((((size_t)(bh * 32 + (ntg >> 1))) * CT + ctl) * 64 + l) * 16 + (size_t)(ntg & 1) * 8;
    *(s16x4*)((char*)hpbh + off) = hbh;
  }

  constexpr int HW = (CTW * 16) / FO;   // heads per wave (=2)
#pragma unroll
  for (int hh = 0; hh < HW; ++hh) {
    float sred[4], dred[4];
#pragma unroll
    for (int r = 0; r < 4; r++) {
      float sv = 0.f, dv = 0.f;
#pragma unroll
      for (int i = hh * CT; i < (hh + 1) * CT; ++i) { sv += s_acc[i][r]; dv += d_acc[i][r]; }
      for (int m = 1; m < 16; m <<= 1) {
        sv += __shfl_xor(sv, m, 64);
        dv += __shfl_xor(dv, m, 64);
      }
      sred[r] = sv * LOG2E;
      dred[r] = dv * LOG2E;
    }
    if (l15 == 0) {
      int ct0 = w4 * CTW + hh * CT;
      int h   = (ct0 * 16) / FO;
      int bh  = b * 8 + h;
      f32x4 sv4; sv4[0] = sred[0]; sv4[1] = sred[1]; sv4[2] = sred[2]; sv4[3] = sred[3];
      *(f32x4*)&sp[bh * 1024 + ntg * 16 + 4 * c] = sv4;
      int s1 = (ntg >> 1) * 16 + 4 * c + 2 * (ntg & 1);
      h2x2 Da; Da[0] = (_Float16)fexp2(dred[0]); Da[1] = (_Float16)fexp2(dred[1]);
      h2x2 Db; Db[0] = (_Float16)fexp2(dred[2]); Db[1] = (_Float16)fexp2(dred[3]);
      h2x2 Ea; Ea[0] = (_Float16)fexp2(0.2f * dred[0]); Ea[1] = (_Float16)fexp2(0.2f * dred[1]);
      h2x2 Eb; Eb[0] = (_Float16)fexp2(0.2f * dred[2]); Eb[1] = (_Float16)fexp2(0.2f * dred[3]);
      u32x2 dw; dw[0] = h2bits(Da); dw[1] = h2bits(Db);
      u32x2 ew; ew[0] = h2bits(Ea); ew[1] = h2bits(Eb);
      *(u32x2*)&Dsw[bh * 512 + s1] = dw;
      *(u32x2*)&Esw[bh * 512 + s1] = ew;
    }
  }
}

// ---------------------------------------------------------------------------
// Kernel A: masked softmax(leaky(s+d)) @ h_prime — packed-fp16 score path
// (exact round-13 structure: direct global hpb loads, dist-1 staging, unrolled).
// ---------------------------------------------------------------------------
template<int CT, bool IS_L0>
__global__ __launch_bounds__(512, 8) void k_attn(
    const float* __restrict__ sp, const uint32_t* __restrict__ Dsw,
    const uint32_t* __restrict__ Esw,
    const short* __restrict__ hpbh,
    const uint32_t* __restrict__ adjt,
    const float* __restrict__ bias,
    void* __restrict__ outh, void* __restrict__ outl)
{
  __shared__ uint32_t Dl[512];
  __shared__ uint32_t El[512];
  __shared__ float redm[8];
  __shared__ float racc[4][(CT + 1) * 4][64];

  int i0   = blockIdx.x;          // 1024
  int xcd  = i0 & 7, slot = i0 >> 3;
  int bh   = xcd * 8 + (slot >> 4);
  int rb   = (slot & 15) * 64;
  int b    = bh >> 3;
  int tid  = threadIdx.x;
  int wid  = tid >> 6;            // 0..7
  int r16  = wid >> 1;            // row tile
  int half = wid & 1;             // mc half
  int l = tid & 63, l15 = l & 15, c = l >> 4;

  uint32_t dw = Dsw[bh * 512 + tid];
  Dl[tid] = dw;
  El[tid] = Esw[bh * 512 + tid];
  h2x2 dv2 = bits2h(dw);
  float mv = fmaxf((float)dv2[0], (float)dv2[1]);
  for (int m = 1; m < 64; m <<= 1) mv = fmaxf(mv, __shfl_xor(mv, m, 64));
  if (l == 0) redm[wid] = mv;
  __syncthreads();
  float Dmax = redm[0];
#pragma unroll
  for (int i = 1; i < 8; i++) Dmax = fmaxf(Dmax, redm[i]);
  float maxd = flog2(Dmax);

  int n = rb + r16 * 16 + l15;
  float svn = sp[bh * 1024 + n];
  float su  = svn + maxd;
  float ub  = fmaxf(su, 0.2f * su);      // >= true row max (leaky monotone)
  float cAf = fexp2(svn - ub + 8.0f);          // x256
  float cBf = fexp2(0.2f * svn - ub + 8.0f);   // x256
  h2x2 cA2; cA2[0] = (_Float16)cAf; cA2[1] = (_Float16)cAf;
  h2x2 cB2; cB2[0] = (_Float16)cBf; cB2[1] = (_Float16)cBf;
  const short* hpbase = hpbh + (size_t)bh * 32 * CT * 512;
  const uint32_t* atile = adjt + ((size_t)(b * 64 + (rb >> 4) + r16) * 32) * 128 + l * 2;

  f32x4 acc[CT];
#pragma unroll
  for (int i = 0; i < CT; i++) acc[i] = (f32x4){0.f, 0.f, 0.f, 0.f};
  f32x4 accp = (f32x4){0.f, 0.f, 0.f, 0.f};
  union { s16x8 s; f16x8 f; } ones;
#pragma unroll
  for (int j = 0; j < 8; j++) ones.s[j] = (short)0x3C00;   // fp16 1.0

  const int mcBeg = half * 16;
  u32x2 nam = *(const u32x2*)(atile + (size_t)mcBeg * 128);
  s16x8 nb[CT];
#pragma unroll
  for (int i = 0; i < CT; i++)
    nb[i] = *(const s16x8*)(hpbase + ((size_t)(mcBeg * CT + i) * 64 + l) * 8);
  u32x4 ndq = *(const u32x4*)&Dl[mcBeg * 16 + 4 * c];
  u32x4 neq = *(const u32x4*)&El[mcBeg * 16 + 4 * c];

#pragma unroll
  for (int t = 0; t < 16; ++t) {
    int mc = mcBeg + t;
    u32x2 am = nam;
    u32x4 dq = ndq, eq = neq;
    union { s16x8 s; f16x8 f; } cb[CT];
#pragma unroll
    for (int i = 0; i < CT; i++) cb[i].s = nb[i];
    if (t < 15) {
      int mcn = mc + 1;
      nam = *(const u32x2*)(atile + (size_t)mcn * 128);
#pragma unroll
      for (int i = 0; i < CT; i++)
        nb[i] = *(const s16x8*)(hpbase + ((size_t)(mcn * CT + i) * 64 + l) * 8);
      ndq = *(const u32x4*)&Dl[mcn * 16 + 4 * c];
      neq = *(const u32x4*)&El[mcn * 16 + 4 * c];
    }

    union { u32x4 w; s16x8 s; f16x8 f; } pu;
#pragma unroll
    for (int tt = 0; tt < 4; ++tt) {
      h2x2 p2 = __builtin_elementwise_max(cA2 * bits2h(dq[tt]), cB2 * bits2h(eq[tt]));
      uint32_t msk = __builtin_amdgcn_perm(0u, am[tt >> 1],
                                           (tt & 1) ? 0x03030202u : 0x01010000u);
      pu.w[tt] = h2bits(p2) & msk;
    }

#pragma unroll
    for (int i = 0; i < CT; i++)
      acc[i] = __builtin_amdgcn_mfma_f32_16x16x32_f16(pu.f, cb[i].f, acc[i], 0, 0, 0);
    accp = __builtin_amdgcn_mfma_f32_16x16x32_f16(pu.f, ones.f, accp, 0, 0, 0);
  }

  if (half == 1) {
#pragma unroll
    for (int i = 0; i < CT; i++)
#pragma unroll
      for (int r = 0; r < 4; r++) racc[r16][i * 4 + r][l] = acc[i][r];
#pragma unroll
    for (int r = 0; r < 4; r++) racc[r16][CT * 4 + r][l] = accp[r];
  }
  __syncthreads();
  if (half == 0) {
#pragma unroll
    for (int i = 0; i < CT; i++)
#pragma unroll
      for (int r = 0; r < 4; r++) acc[i][r] += racc[r16][i * 4 + r][l];
#pragma unroll
    for (int r = 0; r < 4; r++) {
      float rs  = accp[r] + racc[r16][CT * 4 + r][l];
      float inv = frcp(rs);
      int rown  = rb + r16 * 16 + 4 * c + r;
#pragma unroll
      for (int i = 0; i < CT; i++) {
        float v = acc[i][r] * inv;
        int col = i * 16 + l15;
        int h   = bh & 7;
        if (IS_L0) {
          v += bias[col];
          v = v > 0.f ? v : fexp2(v * LOG2E) - 1.f;   // elu
          size_t idx = ((size_t)(b * 1024 + rown)) * 256 + h * 32 + col;
          short vh = f2h(v);
          ((short*)outh)[idx] = vh;
          ((short*)outl)[idx] = f2h(v - h2f(vh));
        } else {
          ((float*)outh)[(((size_t)(b * 8 + h)) * 1024 + rown) * 16 + col] = v;
        }
      }
    }
  }
}

// ---------------------------------------------------------------------------
// Kernel F: mean over heads + bias + log_softmax(16)
// ---------------------------------------------------------------------------
__global__ __launch_bounds__(256) void k_final(
    const float* __restrict__ out1, const float* __restrict__ b1,
    float* __restrict__ out)
{
  int idx = blockIdx.x * 256 + threadIdx.x;
  if (idx >= 8192) return;
  int b = idx >> 10, n = idx & 1023;
  float v[16];
#pragma unroll
  for (int o = 0; o < 16; o++) v[o] = 0.f;
  for (int h = 0; h < 8; h++) {
    const float* p = out1 + (((size_t)(b * 8 + h)) * 1024 + n) * 16;
#pragma unroll
    for (int o = 0; o < 16; o++) v[o] += p[o];
  }
  float mx = -1e30f;
#pragma unroll
  for (int o = 0; o < 16; o++) {
    v[o] = v[o] * 0.125f + b1[o];
    mx = fmaxf(mx, v[o]);
  }
  float s = 0.f;
#pragma unroll
  for (int o = 0; o < 16; o++) s += fexp2((v[o] - mx) * LOG2E);
  float lse = flog2(s) * LN2;
#pragma unroll
  for (int o = 0; o < 16; o++) out[(size_t)idx * 16 + o] = v[o] - mx - lse;
}

// ---------------------------------------------------------------------------
extern "C" void kernel_launch(void* const* d_in, const int* in_sizes, int n_in,
                              void* d_out, int out_size, void* d_ws, size_t ws_size,
                              hipStream_t stream) {
  const float*   x     = (const float*)d_in[0];
  const int*     verts = (const int*)d_in[1];
  const void*    adj   = (const void*)d_in[2];   // int32 or uint8 — auto-detected
  const float*   emb   = (const float*)d_in[3];
  const float*   w0    = (const float*)d_in[4];
  const float*   as0   = (const float*)d_in[5];
  const float*   ad0   = (const float*)d_in[6];
  const float*   b0    = (const float*)d_in[7];
  const float*   w1    = (const float*)d_in[8];
  const float*   as1   = (const float*)d_in[9];
  const float*   ad1   = (const float*)d_in[10];
  const float*   b1    = (const float*)d_in[11];

  char* ws = (char*)d_ws;
  const size_t MB = 1ull << 20;
  const size_t KB = 1024;
  short* hpb0h = (short*)(ws);                         // 4 MB (dead after attn0)
  float* out1  = (float*)(ws);                         // 4 MB (aliases hpb0h)
  short* x1h   = (short*)(ws + 4 * MB);                // 4 MB
  short* x1l   = (short*)(ws + 8 * MB);                // 4 MB
  short* hpb1h = (short*)(ws + 12 * MB);               // 2 MB
  uint32_t* adjt = (uint32_t*)(ws + 14 * MB);          // 8 MB
  float* s0    = (float*)(ws + 22 * MB);               // 256 KB
  float* s1    = (float*)(ws + 22 * MB + 256 * KB);    // 256 KB
  short* wf0h  = (short*)(ws + 22 * MB + 512 * KB);    // 64 KB each
  short* wf0l  = (short*)(ws + 22 * MB + 576 * KB);
  short* wf1h  = (short*)(ws + 22 * MB + 640 * KB);
  short* wf1l  = (short*)(ws + 22 * MB + 704 * KB);
  uint32_t* Dsw0 = (uint32_t*)(ws + 22 * MB + 768 * KB);   // 128 KB each
  uint32_t* Esw0 = (uint32_t*)(ws + 22 * MB + 896 * KB);
  uint32_t* Dsw1 = (uint32_t*)(ws + 23 * MB);
  uint32_t* Esw1 = (uint32_t*)(ws + 23 * MB + 128 * KB);
  float* out   = (float*)d_out;

  k_megaprep<<<288, 256, 0, stream>>>(adj, adjt, w0, w1, wf0h, wf0l, wf1h, wf1l);
  k_hprime<128, 32, true><<<512, 256, 0, stream>>>(nullptr, nullptr, x, verts, emb,
                                             wf0h, wf0l, as0, ad0,
                                             hpb0h, s0, Dsw0, Esw0);
  k_attn<2, true><<<1024, 512, 0, stream>>>(s0, Dsw0, Esw0, hpb0h, adjt,
                                            b0, (void*)x1h, (void*)x1l);
  k_hprime<256, 16, false><<<512, 256, 0, stream>>>(x1h, x1l, nullptr, nullptr, nullptr,
                                             wf1h, wf1l, as1, ad1,
                                             hpb1h, s1, Dsw1, Esw1);
  k_attn<1, false><<<1024, 512, 0, stream>>>(s1, Dsw1, Esw1, hpb1h, adjt,
                                             b1, (void*)out1, nullptr);
  k_final<<<32, 256, 0, stream>>>(out1, b1, out);
}